// Round 1
// baseline (151.054 us; speedup 1.0000x reference)
//
#include <hip/hip_runtime.h>
#include <hip/hip_bf16.h>
#include <float.h>

#define B_ 64
#define L_ 1024
#define D_ 1024
#define NSPLIT 16
#define CHUNK 64              // L_/NSPLIT
#define PSTRIDE 1028          // D_ + 4 (keeps float4 alignment: 1028*4 bytes % 16 == 0)

typedef __bf16 bf16x8 __attribute__((ext_vector_type(8)));
typedef float f32x4 __attribute__((ext_vector_type(4)));

__device__ inline unsigned short f2bf(float x) {
    unsigned int u = __float_as_uint(x);
    unsigned int lsb = (u >> 16) & 1u;
    u += 0x7fffu + lsb;           // round-to-nearest-even
    return (unsigned short)(u >> 16);
}

// ---------------------------------------------------------------------------
// Partial masked attention: one block = one (batch, L-chunk of 64 rows).
// Writes unnormalized O[1024], local max m, local sumexp to part[].
// ---------------------------------------------------------------------------
__global__ __launch_bounds__(256) void attn_partial_kernel(
    const float* __restrict__ q,      // [B][D]
    const float* __restrict__ K,      // [B][L][D]
    const float* __restrict__ V,      // [B][L][D]
    const int*   __restrict__ mask,   // [B][L] (0/1)
    float* __restrict__ part)         // [B*NSPLIT][PSTRIDE]
{
    const int bid  = blockIdx.x;
    const int b    = bid >> 4;        // NSPLIT == 16
    const int sp   = bid & 15;
    const int l0   = sp * CHUNK;
    const int tid  = threadIdx.x;
    const int wave = tid >> 6;
    const int lane = tid & 63;

    __shared__ float qs[D_];
    __shared__ float sc[CHUNK];
    __shared__ float pv[CHUNK];

    // stage q row into LDS (4 KB, coalesced float4)
    float4 qv = reinterpret_cast<const float4*>(q + (size_t)b * D_)[tid];
    reinterpret_cast<float4*>(qs)[tid] = qv;
    __syncthreads();

    // scores: wave w handles rows w*16 .. w*16+15 (sequential), skip masked rows
    const float4* qrow = reinterpret_cast<const float4*>(qs);
    for (int r = 0; r < 16; ++r) {
        int l  = wave * 16 + r;
        int gl = l0 + l;
        int mv = mask[(size_t)b * L_ + gl];     // uniform across wave
        if (!mv) { if (lane == 0) sc[l] = -FLT_MAX; continue; }
        const float4* krow = reinterpret_cast<const float4*>(K + ((size_t)b * L_ + gl) * D_);
        float acc = 0.f;
        #pragma unroll
        for (int rep = 0; rep < 4; ++rep) {
            float4 kv = krow[lane + rep * 64];
            float4 qq = qrow[lane + rep * 64];
            acc += kv.x * qq.x + kv.y * qq.y + kv.z * qq.z + kv.w * qq.w;
        }
        #pragma unroll
        for (int off = 32; off > 0; off >>= 1) acc += __shfl_xor(acc, off, 64);
        if (lane == 0) sc[l] = acc * 0.03125f;  // 1/sqrt(1024)
    }
    __syncthreads();

    // chunk-local max (redundant per thread; 64 LDS reads, cheap)
    float m = -FLT_MAX;
    #pragma unroll
    for (int l = 0; l < CHUNK; ++l) m = fmaxf(m, sc[l]);

    if (tid < CHUNK) {
        float s = sc[tid];
        pv[tid] = (s == -FLT_MAX) ? 0.f : __expf(s - m);   // guard all-masked chunk
    }
    __syncthreads();

    // PV: thread owns 4 consecutive d; skip zero-weight rows (saves V traffic)
    float se = 0.f;
    float ax = 0.f, ay = 0.f, az = 0.f, aw = 0.f;
    const float4* vbase = reinterpret_cast<const float4*>(V + ((size_t)b * L_ + l0) * D_);
    for (int l = 0; l < CHUNK; ++l) {
        float pl = pv[l];
        se += pl;
        if (pl == 0.f) continue;                // uniform branch
        float4 vv = vbase[l * (D_ / 4) + tid];
        ax += pl * vv.x; ay += pl * vv.y; az += pl * vv.z; aw += pl * vv.w;
    }

    float* po = part + (size_t)bid * PSTRIDE;
    float4 o; o.x = ax; o.y = ay; o.z = az; o.w = aw;
    reinterpret_cast<float4*>(po)[tid] = o;
    if (tid == 0) { po[D_] = m; po[D_ + 1] = se; }
}

// ---------------------------------------------------------------------------
// Combine NSPLIT partials per batch -> normalized ctx row, stored as bf16.
// ---------------------------------------------------------------------------
__global__ __launch_bounds__(256) void combine_kernel(
    const float* __restrict__ part,
    unsigned short* __restrict__ ctxb)   // [B][D] bf16
{
    const int b   = blockIdx.x;
    const int tid = threadIdx.x;
    const float* pb = part + (size_t)b * NSPLIT * PSTRIDE;

    float ms[NSPLIT];
    float gm = -FLT_MAX;
    #pragma unroll
    for (int sp = 0; sp < NSPLIT; ++sp) {
        ms[sp] = pb[(size_t)sp * PSTRIDE + D_];
        gm = fmaxf(gm, ms[sp]);
    }
    float sca[NSPLIT];
    float denom = 0.f;
    #pragma unroll
    for (int sp = 0; sp < NSPLIT; ++sp) {
        float e = (ms[sp] == -FLT_MAX) ? 0.f : __expf(ms[sp] - gm);
        sca[sp] = e;
        denom += pb[(size_t)sp * PSTRIDE + D_ + 1] * e;
    }
    float inv = 1.f / denom;   // denom > 0: l=0 always valid

    float ax = 0.f, ay = 0.f, az = 0.f, aw = 0.f;
    #pragma unroll
    for (int sp = 0; sp < NSPLIT; ++sp) {
        if (sca[sp] == 0.f) continue;
        float4 o = reinterpret_cast<const float4*>(pb + (size_t)sp * PSTRIDE)[tid];
        float s = sca[sp] * inv;
        ax += s * o.x; ay += s * o.y; az += s * o.z; aw += s * o.w;
    }
    ushort4 u;
    u.x = f2bf(ax); u.y = f2bf(ay); u.z = f2bf(az); u.w = f2bf(aw);
    reinterpret_cast<ushort4*>(ctxb)[(size_t)b * (D_ / 4) + tid] = u;
}

// ---------------------------------------------------------------------------
// fp32 -> bf16 weight conversion (runs every call; 4 MB read each)
// ---------------------------------------------------------------------------
__global__ __launch_bounds__(256) void convert_kernel(
    const float* __restrict__ src, unsigned short* __restrict__ dst, int n4)
{
    int i = blockIdx.x * 256 + threadIdx.x;
    if (i >= n4) return;
    float4 v = reinterpret_cast<const float4*>(src)[i];
    ushort4 u;
    u.x = f2bf(v.x); u.y = f2bf(v.y); u.z = f2bf(v.z); u.w = f2bf(v.w);
    reinterpret_cast<ushort4*>(dst)[i] = u;
}

// ---------------------------------------------------------------------------
// out[m][n] = qin[m][n] + bias[n] + sum_k ctx[m][k] * W[n][k]   (bf16 MFMA)
// grid: 256 blocks = one 16x16 C tile each; 4 waves split K (256 each) + LDS reduce.
// ---------------------------------------------------------------------------
__global__ __launch_bounds__(256) void proj_kernel(
    const unsigned short* __restrict__ Abf,   // ctx bf16 [64][1024]
    const unsigned short* __restrict__ Wbf,   // W  bf16 [1024][1024]
    const float* __restrict__ qin,            // [64][1024]
    const float* __restrict__ bias,           // [1024]
    float* __restrict__ out)                  // [64][1024]
{
    const int tid  = threadIdx.x;
    const int wave = tid >> 6;
    const int lane = tid & 63;
    const int m0   = (blockIdx.x & 3) * 16;
    const int n0   = (blockIdx.x >> 2) * 16;
    const int r    = lane & 15;
    const int g    = lane >> 4;

    // A frag: lane holds A[m0+r][g*8 + j]; B frag: lane holds W[n0+r][g*8 + j]
    const bf16x8* aptr = reinterpret_cast<const bf16x8*>(
        Abf + (size_t)(m0 + r) * D_ + g * 8 + wave * 256);
    const bf16x8* bptr = reinterpret_cast<const bf16x8*>(
        Wbf + (size_t)(n0 + r) * D_ + g * 8 + wave * 256);

    f32x4 acc = {0.f, 0.f, 0.f, 0.f};
    #pragma unroll
    for (int kk = 0; kk < 8; ++kk) {          // 8 steps of K=32 -> 256 per wave
        bf16x8 a  = aptr[kk * 4];
        bf16x8 bb = bptr[kk * 4];
        acc = __builtin_amdgcn_mfma_f32_16x16x32_bf16(a, bb, acc, 0, 0, 0);
    }

    __shared__ float red[1024];
    #pragma unroll
    for (int i = 0; i < 4; ++i) red[wave * 256 + lane * 4 + i] = acc[i];
    __syncthreads();

    int ol = tid >> 2, oi = tid & 3;          // ol = original lane, oi = reg idx
    float v = red[ol * 4 + oi] + red[256 + ol * 4 + oi]
            + red[512 + ol * 4 + oi] + red[768 + ol * 4 + oi];
    int row = m0 + ((ol >> 4) * 4 + oi);      // C/D: row=(lane>>4)*4+reg
    int col = n0 + (ol & 15);                 //      col=lane&15
    out[(size_t)row * D_ + col] = qin[(size_t)row * D_ + col] + bias[col] + v;
}

// ---------------------------------------------------------------------------
extern "C" void kernel_launch(void* const* d_in, const int* in_sizes, int n_in,
                              void* d_out, int out_size, void* d_ws, size_t ws_size,
                              hipStream_t stream) {
    const float* img_q    = (const float*)d_in[0];
    const float* txt_q    = (const float*)d_in[1];
    const float* K_img    = (const float*)d_in[2];
    const float* V_img    = (const float*)d_in[3];
    const int*   img_mask = (const int*)  d_in[4];
    const float* K_txt    = (const float*)d_in[5];
    const float* V_txt    = (const float*)d_in[6];
    const int*   txt_mask = (const int*)  d_in[7];
    const float* W_img    = (const float*)d_in[8];
    const float* b_img    = (const float*)d_in[9];
    const float* W_txt    = (const float*)d_in[10];
    const float* b_txt    = (const float*)d_in[11];

    float* out_img = (float*)d_out;             // [64][1024]
    float* out_txt = (float*)d_out + B_ * D_;   // [64][1024]

    char* ws = (char*)d_ws;
    float* part = (float*)ws;                                   // 64*16*1028 f32
    size_t part_bytes = (size_t)B_ * NSPLIT * PSTRIDE * sizeof(float);
    unsigned short* Wimg_bf = (unsigned short*)(ws + part_bytes);
    unsigned short* Wtxt_bf = Wimg_bf + (size_t)D_ * D_;
    unsigned short* ctx_bf  = Wtxt_bf + (size_t)D_ * D_;

    // weight conversion (independent of attention; cheap)
    convert_kernel<<<1024, 256, 0, stream>>>(W_img, Wimg_bf, D_ * D_ / 4);
    convert_kernel<<<1024, 256, 0, stream>>>(W_txt, Wtxt_bf, D_ * D_ / 4);

    // stage 1: ctx_img = attn(txt_q, K_img, V_img, img_mask); img_out = img_q + ctx@W^T + b
    attn_partial_kernel<<<B_ * NSPLIT, 256, 0, stream>>>(txt_q, K_img, V_img, img_mask, part);
    combine_kernel<<<B_, 256, 0, stream>>>(part, ctx_bf);
    proj_kernel<<<256, 256, 0, stream>>>(ctx_bf, Wimg_bf, img_q, b_img, out_img);

    // stage 2: ctx_txt = attn(img_out, K_txt, V_txt, txt_mask); txt_out = txt_q + ctx@W^T + b
    attn_partial_kernel<<<B_ * NSPLIT, 256, 0, stream>>>(out_img, K_txt, V_txt, txt_mask, part);
    combine_kernel<<<B_, 256, 0, stream>>>(part, ctx_bf);
    proj_kernel<<<256, 256, 0, stream>>>(ctx_bf, Wtxt_bf, txt_q, b_txt, out_txt);
}

// Round 2
// 139.930 us; speedup vs baseline: 1.0795x; 1.0795x over previous
//
#include <hip/hip_runtime.h>
#include <hip/hip_bf16.h>
#include <float.h>

#define B_ 64
#define L_ 1024
#define D_ 1024
#define NSPLIT 16
#define CHUNK 64              // L_/NSPLIT
#define PSTRIDE 1028          // D_ + 4 (keeps float4 alignment)

typedef __bf16 bf16x8 __attribute__((ext_vector_type(8)));
typedef float f32x4 __attribute__((ext_vector_type(4)));

__device__ inline unsigned short f2bf(float x) {
    unsigned int u = __float_as_uint(x);
    unsigned int lsb = (u >> 16) & 1u;
    u += 0x7fffu + lsb;           // round-to-nearest-even
    return (unsigned short)(u >> 16);
}

// ---------------------------------------------------------------------------
// Partial masked attention: one block = one (batch, L-chunk of 64 rows).
// Ballot-compacted valid-row list -> branch-free batched streaming.
// ---------------------------------------------------------------------------
__global__ __launch_bounds__(256, 4) void attn_partial_kernel(
    const float* __restrict__ q,      // [B][D]
    const float* __restrict__ K,      // [B][L][D]
    const float* __restrict__ V,      // [B][L][D]
    const int*   __restrict__ mask,   // [B][L] (0/1)
    float* __restrict__ part)         // [B*NSPLIT][PSTRIDE]
{
    const int bid  = blockIdx.x;
    const int b    = bid >> 4;        // NSPLIT == 16
    const int sp   = bid & 15;
    const int l0   = sp * CHUNK;
    const int tid  = threadIdx.x;
    const int wave = tid >> 6;
    const int lane = tid & 63;

    __shared__ int   vidx[CHUNK];
    __shared__ float sc[CHUNK];
    __shared__ float pw[CHUNK];
    __shared__ int   nvalid;

    // --- q row into registers (same row for all waves; L2-hot across blocks)
    const float4* qptr = reinterpret_cast<const float4*>(q + (size_t)b * D_);
    float4 qreg[4];
    #pragma unroll
    for (int rep = 0; rep < 4; ++rep) qreg[rep] = qptr[lane + rep * 64];

    // --- compaction (wave 0): vidx[0..nv) = valid rows, pad rest with first valid
    if (wave == 0) {
        int mv = mask[(size_t)b * L_ + l0 + lane];
        unsigned long long bal = __ballot(mv != 0);
        int nv   = __popcll(bal);
        int padv = bal ? (__ffsll((long long)bal) - 1) : 0;
        int rank = __popcll(bal & ((1ull << lane) - 1));
        if (mv) vidx[rank] = lane;
        if (lane >= nv) vidx[lane] = padv;
        if (lane == 0) nvalid = nv;
    }
    __syncthreads();
    const int nv  = nvalid;
    const int nvp = (nv + 7) & ~7;    // padded count (multiple of 8)

    // --- scores over compacted rows: wave w handles jj = w, w+8, ... plus jj+4
    const float* Kb = K + ((size_t)b * L_ + l0) * D_;
    for (int jj = wave; jj < nvp; jj += 8) {
        int j2 = jj + 4;              // always < nvp (see padding math)
        const float4* k0 = reinterpret_cast<const float4*>(Kb + (size_t)vidx[jj] * D_);
        const float4* k1 = reinterpret_cast<const float4*>(Kb + (size_t)vidx[j2] * D_);
        float a0 = 0.f, a1 = 0.f;
        float4 kv0[4], kv1[4];
        #pragma unroll
        for (int rep = 0; rep < 4; ++rep) { kv0[rep] = k0[lane + rep * 64];
                                            kv1[rep] = k1[lane + rep * 64]; }
        #pragma unroll
        for (int rep = 0; rep < 4; ++rep) {
            a0 += kv0[rep].x * qreg[rep].x + kv0[rep].y * qreg[rep].y
                + kv0[rep].z * qreg[rep].z + kv0[rep].w * qreg[rep].w;
            a1 += kv1[rep].x * qreg[rep].x + kv1[rep].y * qreg[rep].y
                + kv1[rep].z * qreg[rep].z + kv1[rep].w * qreg[rep].w;
        }
        #pragma unroll
        for (int off = 32; off > 0; off >>= 1) {
            a0 += __shfl_xor(a0, off, 64);
            a1 += __shfl_xor(a1, off, 64);
        }
        if (lane == 0) { sc[jj] = a0 * 0.03125f; sc[j2] = a1 * 0.03125f; }
    }
    __syncthreads();

    // --- chunk max over valid scores (redundant per thread, <=64 LDS reads)
    float m = -FLT_MAX;
    for (int j = 0; j < nv; ++j) m = fmaxf(m, sc[j]);

    if (tid < CHUNK) pw[tid] = (tid < nv) ? __expf(sc[tid] - m) : 0.f;
    __syncthreads();

    // --- PV: batch 8 rows/iter, 8 independent float4 loads in flight
    float se = 0.f;
    float ax = 0.f, ay = 0.f, az = 0.f, aw = 0.f;
    const float4* vbase = reinterpret_cast<const float4*>(V + ((size_t)b * L_ + l0) * D_);
    for (int j = 0; j < nvp; j += 8) {
        float p[8]; int ix[8];
        #pragma unroll
        for (int t = 0; t < 8; ++t) { p[t] = pw[j + t]; ix[t] = vidx[j + t]; }
        float4 vv[8];
        #pragma unroll
        for (int t = 0; t < 8; ++t) vv[t] = vbase[(size_t)ix[t] * (D_ / 4) + tid];
        #pragma unroll
        for (int t = 0; t < 8; ++t) {
            se += p[t];
            ax += p[t] * vv[t].x; ay += p[t] * vv[t].y;
            az += p[t] * vv[t].z; aw += p[t] * vv[t].w;
        }
    }

    float* po = part + (size_t)bid * PSTRIDE;
    float4 o; o.x = ax; o.y = ay; o.z = az; o.w = aw;
    reinterpret_cast<float4*>(po)[tid] = o;
    if (tid == 0) { po[D_] = m; po[D_ + 1] = se; }
}

// ---------------------------------------------------------------------------
// Combine NSPLIT partials per batch -> normalized ctx row, stored as bf16.
// ---------------------------------------------------------------------------
__global__ __launch_bounds__(256) void combine_kernel(
    const float* __restrict__ part,
    unsigned short* __restrict__ ctxb)   // [B][D] bf16
{
    const int b   = blockIdx.x;
    const int tid = threadIdx.x;
    const float* pb = part + (size_t)b * NSPLIT * PSTRIDE;

    float ms[NSPLIT];
    float gm = -FLT_MAX;
    #pragma unroll
    for (int sp = 0; sp < NSPLIT; ++sp) {
        ms[sp] = pb[(size_t)sp * PSTRIDE + D_];
        gm = fmaxf(gm, ms[sp]);
    }
    float sca[NSPLIT];
    float denom = 0.f;
    #pragma unroll
    for (int sp = 0; sp < NSPLIT; ++sp) {
        float e = (ms[sp] == -FLT_MAX) ? 0.f : __expf(ms[sp] - gm);
        sca[sp] = e;
        denom += pb[(size_t)sp * PSTRIDE + D_ + 1] * e;
    }
    float inv = 1.f / denom;   // denom > 0: l=0 always valid

    float ax = 0.f, ay = 0.f, az = 0.f, aw = 0.f;
    #pragma unroll
    for (int sp = 0; sp < NSPLIT; ++sp) {
        if (sca[sp] == 0.f) continue;
        float4 o = reinterpret_cast<const float4*>(pb + (size_t)sp * PSTRIDE)[tid];
        float s = sca[sp] * inv;
        ax += s * o.x; ay += s * o.y; az += s * o.z; aw += s * o.w;
    }
    ushort4 u;
    u.x = f2bf(ax); u.y = f2bf(ay); u.z = f2bf(az); u.w = f2bf(aw);
    reinterpret_cast<ushort4*>(ctxb)[(size_t)b * (D_ / 4) + tid] = u;
}

// ---------------------------------------------------------------------------
// fp32 -> bf16 weight conversion
// ---------------------------------------------------------------------------
__global__ __launch_bounds__(256) void convert_kernel(
    const float* __restrict__ src, unsigned short* __restrict__ dst, int n4)
{
    int i = blockIdx.x * 256 + threadIdx.x;
    if (i >= n4) return;
    float4 v = reinterpret_cast<const float4*>(src)[i];
    ushort4 u;
    u.x = f2bf(v.x); u.y = f2bf(v.y); u.z = f2bf(v.z); u.w = f2bf(v.w);
    reinterpret_cast<ushort4*>(dst)[i] = u;
}

// ---------------------------------------------------------------------------
// out[m][n] = qin[m][n] + bias[n] + sum_k ctx[m][k] * W[n][k]   (bf16 MFMA)
// grid: 256 blocks = one 16x16 C tile each; 4 waves split K (256 each) + LDS reduce.
// ---------------------------------------------------------------------------
__global__ __launch_bounds__(256) void proj_kernel(
    const unsigned short* __restrict__ Abf,   // ctx bf16 [64][1024]
    const unsigned short* __restrict__ Wbf,   // W  bf16 [1024][1024]
    const float* __restrict__ qin,            // [64][1024]
    const float* __restrict__ bias,           // [1024]
    float* __restrict__ out)                  // [64][1024]
{
    const int tid  = threadIdx.x;
    const int wave = tid >> 6;
    const int lane = tid & 63;
    const int m0   = (blockIdx.x & 3) * 16;
    const int n0   = (blockIdx.x >> 2) * 16;
    const int r    = lane & 15;
    const int g    = lane >> 4;

    const bf16x8* aptr = reinterpret_cast<const bf16x8*>(
        Abf + (size_t)(m0 + r) * D_ + g * 8 + wave * 256);
    const bf16x8* bptr = reinterpret_cast<const bf16x8*>(
        Wbf + (size_t)(n0 + r) * D_ + g * 8 + wave * 256);

    f32x4 acc = {0.f, 0.f, 0.f, 0.f};
    #pragma unroll
    for (int kk = 0; kk < 8; ++kk) {          // 8 steps of K=32 -> 256 per wave
        bf16x8 a  = aptr[kk * 4];
        bf16x8 bb = bptr[kk * 4];
        acc = __builtin_amdgcn_mfma_f32_16x16x32_bf16(a, bb, acc, 0, 0, 0);
    }

    __shared__ float red[1024];
    #pragma unroll
    for (int i = 0; i < 4; ++i) red[wave * 256 + lane * 4 + i] = acc[i];
    __syncthreads();

    int ol = tid >> 2, oi = tid & 3;          // ol = original lane, oi = reg idx
    float v = red[ol * 4 + oi] + red[256 + ol * 4 + oi]
            + red[512 + ol * 4 + oi] + red[768 + ol * 4 + oi];
    int row = m0 + ((ol >> 4) * 4 + oi);      // C/D: row=(lane>>4)*4+reg
    int col = n0 + (ol & 15);                 //      col=lane&15
    out[(size_t)row * D_ + col] = qin[(size_t)row * D_ + col] + bias[col] + v;
}

// ---------------------------------------------------------------------------
extern "C" void kernel_launch(void* const* d_in, const int* in_sizes, int n_in,
                              void* d_out, int out_size, void* d_ws, size_t ws_size,
                              hipStream_t stream) {
    const float* img_q    = (const float*)d_in[0];
    const float* txt_q    = (const float*)d_in[1];
    const float* K_img    = (const float*)d_in[2];
    const float* V_img    = (const float*)d_in[3];
    const int*   img_mask = (const int*)  d_in[4];
    const float* K_txt    = (const float*)d_in[5];
    const float* V_txt    = (const float*)d_in[6];
    const int*   txt_mask = (const int*)  d_in[7];
    const float* W_img    = (const float*)d_in[8];
    const float* b_img    = (const float*)d_in[9];
    const float* W_txt    = (const float*)d_in[10];
    const float* b_txt    = (const float*)d_in[11];

    float* out_img = (float*)d_out;             // [64][1024]
    float* out_txt = (float*)d_out + B_ * D_;   // [64][1024]

    char* ws = (char*)d_ws;
    float* part = (float*)ws;                                   // 64*16*1028 f32
    size_t part_bytes = (size_t)B_ * NSPLIT * PSTRIDE * sizeof(float);
    unsigned short* Wimg_bf = (unsigned short*)(ws + part_bytes);
    unsigned short* Wtxt_bf = Wimg_bf + (size_t)D_ * D_;
    unsigned short* ctx_bf  = Wtxt_bf + (size_t)D_ * D_;

    // weight conversion (independent of attention; cheap)
    convert_kernel<<<1024, 256, 0, stream>>>(W_img, Wimg_bf, D_ * D_ / 4);
    convert_kernel<<<1024, 256, 0, stream>>>(W_txt, Wtxt_bf, D_ * D_ / 4);

    // stage 1: ctx_img = attn(txt_q, K_img, V_img, img_mask); img_out = img_q + ctx@W^T + b
    attn_partial_kernel<<<B_ * NSPLIT, 256, 0, stream>>>(txt_q, K_img, V_img, img_mask, part);
    combine_kernel<<<B_, 256, 0, stream>>>(part, ctx_bf);
    proj_kernel<<<256, 256, 0, stream>>>(ctx_bf, Wimg_bf, img_q, b_img, out_img);

    // stage 2: ctx_txt = attn(img_out, K_txt, V_txt, txt_mask); txt_out = txt_q + ctx@W^T + b
    attn_partial_kernel<<<B_ * NSPLIT, 256, 0, stream>>>(out_img, K_txt, V_txt, txt_mask, part);
    combine_kernel<<<B_, 256, 0, stream>>>(part, ctx_bf);
    proj_kernel<<<256, 256, 0, stream>>>(ctx_bf, Wtxt_bf, txt_q, b_txt, out_txt);
}

// Round 3
// 132.505 us; speedup vs baseline: 1.1400x; 1.0560x over previous
//
#include <hip/hip_runtime.h>
#include <hip/hip_bf16.h>
#include <float.h>

#define B_ 64
#define L_ 1024
#define D_ 1024
#define NSPLIT 8
#define CHUNK 128             // L_/NSPLIT
#define PSTRIDE 1028          // D_ + 4 (keeps float4 alignment)

typedef __bf16 bf16x8 __attribute__((ext_vector_type(8)));
typedef float f32x4 __attribute__((ext_vector_type(4)));

__device__ inline unsigned short f2bf(float x) {
    unsigned int u = __float_as_uint(x);
    unsigned int lsb = (u >> 16) & 1u;
    u += 0x7fffu + lsb;           // round-to-nearest-even
    return (unsigned short)(u >> 16);
}

// ---------------------------------------------------------------------------
// Partial masked attention: one block (512 thr) = one (batch, chunk of 128 rows).
// Ballot-compacted valid rows -> branch-free batched streaming.
// grid = 64*8 = 512 blocks = exactly 2 blocks/CU (16 waves).
// ---------------------------------------------------------------------------
__global__ __launch_bounds__(512, 4) void attn_partial_kernel(
    const float* __restrict__ q,      // [B][D]
    const float* __restrict__ K,      // [B][L][D]
    const float* __restrict__ V,      // [B][L][D]
    const int*   __restrict__ mask,   // [B][L] (0/1)
    float* __restrict__ part)         // [B*NSPLIT][PSTRIDE]
{
    const int bid  = blockIdx.x;
    const int b    = bid >> 3;        // NSPLIT == 8
    const int sp   = bid & 7;
    const int l0   = sp * CHUNK;
    const int tid  = threadIdx.x;
    const int wave = tid >> 6;
    const int lane = tid & 63;

    __shared__ int   vidx[CHUNK];
    __shared__ float sc[CHUNK];
    __shared__ float pw[CHUNK];
    __shared__ int   nvalid;

    // --- q row into registers per wave (L1/L2-hot, redundant across waves)
    const float4* qptr = reinterpret_cast<const float4*>(q + (size_t)b * D_);
    float4 qreg[4];
    #pragma unroll
    for (int rep = 0; rep < 4; ++rep) qreg[rep] = qptr[lane + rep * 64];

    // --- compaction (wave 0 handles both 64-row halves)
    if (wave == 0) {
        const int* mp = mask + (size_t)b * L_ + l0;
        int mv0 = mp[lane];
        int mv1 = mp[64 + lane];
        unsigned long long bal0 = __ballot(mv0 != 0);
        unsigned long long bal1 = __ballot(mv1 != 0);
        int n0 = __popcll(bal0);
        int nv = n0 + __popcll(bal1);
        unsigned long long lt = (1ull << lane) - 1;
        if (mv0) vidx[__popcll(bal0 & lt)] = lane;
        if (mv1) vidx[n0 + __popcll(bal1 & lt)] = 64 + lane;
        int padv = bal0 ? (__ffsll((long long)bal0) - 1)
                        : (bal1 ? 64 + __ffsll((long long)bal1) - 1 : 0);
        if (nv + lane < CHUNK) vidx[nv + lane] = padv;   // pad tail with a valid row
        if (lane == 0) nvalid = nv;
    }
    __syncthreads();
    const int nv    = nvalid;
    const int nvp8  = (nv + 7)  & ~7;     // PV batch padding
    const int nvp16 = (nv + 15) & ~15;    // score batch padding (16 rows/iter)

    // --- scores: wave w handles rows jj=w(+16k) and jj+8; 8 loads in flight/thread
    const float* Kb = K + ((size_t)b * L_ + l0) * D_;
    for (int jj = wave; jj < nvp16; jj += 16) {
        int j2 = jj + 8;
        const float4* k0 = reinterpret_cast<const float4*>(Kb + vidx[jj] * D_);
        const float4* k1 = reinterpret_cast<const float4*>(Kb + vidx[j2] * D_);
        float4 kv0[4], kv1[4];
        #pragma unroll
        for (int rep = 0; rep < 4; ++rep) { kv0[rep] = k0[lane + rep * 64];
                                            kv1[rep] = k1[lane + rep * 64]; }
        // split accumulator chains for ILP
        float a0a = 0.f, a0b = 0.f, a1a = 0.f, a1b = 0.f;
        #pragma unroll
        for (int rep = 0; rep < 4; rep += 2) {
            a0a += kv0[rep].x * qreg[rep].x + kv0[rep].y * qreg[rep].y
                 + kv0[rep].z * qreg[rep].z + kv0[rep].w * qreg[rep].w;
            a0b += kv0[rep+1].x * qreg[rep+1].x + kv0[rep+1].y * qreg[rep+1].y
                 + kv0[rep+1].z * qreg[rep+1].z + kv0[rep+1].w * qreg[rep+1].w;
            a1a += kv1[rep].x * qreg[rep].x + kv1[rep].y * qreg[rep].y
                 + kv1[rep].z * qreg[rep].z + kv1[rep].w * qreg[rep].w;
            a1b += kv1[rep+1].x * qreg[rep+1].x + kv1[rep+1].y * qreg[rep+1].y
                 + kv1[rep+1].z * qreg[rep+1].z + kv1[rep+1].w * qreg[rep+1].w;
        }
        float a0 = a0a + a0b, a1 = a1a + a1b;
        #pragma unroll
        for (int off = 32; off > 0; off >>= 1) {
            a0 += __shfl_xor(a0, off, 64);
            a1 += __shfl_xor(a1, off, 64);
        }
        if (lane == 0) { sc[jj] = a0 * 0.03125f; sc[j2] = a1 * 0.03125f; }
    }
    __syncthreads();

    // --- chunk max: 2 LDS reads + 6-shfl reduce (per wave, redundant)
    float m = -FLT_MAX;
    if (lane < nv)      m = sc[lane];
    if (lane + 64 < nv) m = fmaxf(m, sc[lane + 64]);
    #pragma unroll
    for (int off = 32; off > 0; off >>= 1) m = fmaxf(m, __shfl_xor(m, off, 64));

    if (tid < CHUNK) pw[tid] = (tid < nv) ? __expf(sc[tid] - m) : 0.f;
    __syncthreads();

    // --- PV: 512 threads own float2 d-slices; 8 rows/iter -> 8 loads in flight
    float se = 0.f, ax = 0.f, ay = 0.f;
    const float2* vbase = reinterpret_cast<const float2*>(V + ((size_t)b * L_ + l0) * D_);
    for (int j = 0; j < nvp8; j += 8) {
        float p[8]; int ix[8];
        #pragma unroll
        for (int t = 0; t < 8; ++t) { p[t] = pw[j + t]; ix[t] = vidx[j + t]; }
        float2 vv[8];
        #pragma unroll
        for (int t = 0; t < 8; ++t) vv[t] = vbase[ix[t] * (D_ / 2) + tid];
        #pragma unroll
        for (int t = 0; t < 8; ++t) {
            se += p[t];
            ax += p[t] * vv[t].x; ay += p[t] * vv[t].y;
        }
    }

    float* po = part + (size_t)bid * PSTRIDE;
    float2 o; o.x = ax; o.y = ay;
    reinterpret_cast<float2*>(po)[tid] = o;
    if (tid == 0) { po[D_] = m; po[D_ + 1] = se; }
}

// ---------------------------------------------------------------------------
// Combine NSPLIT partials per batch -> normalized ctx row, stored as bf16.
// ---------------------------------------------------------------------------
__global__ __launch_bounds__(256) void combine_kernel(
    const float* __restrict__ part,
    unsigned short* __restrict__ ctxb)   // [B][D] bf16
{
    const int b   = blockIdx.x;
    const int tid = threadIdx.x;
    const float* pb = part + (size_t)b * NSPLIT * PSTRIDE;

    float ms[NSPLIT];
    float gm = -FLT_MAX;
    #pragma unroll
    for (int sp = 0; sp < NSPLIT; ++sp) {
        ms[sp] = pb[(size_t)sp * PSTRIDE + D_];
        gm = fmaxf(gm, ms[sp]);
    }
    float sca[NSPLIT];
    float denom = 0.f;
    #pragma unroll
    for (int sp = 0; sp < NSPLIT; ++sp) {
        float e = (ms[sp] == -FLT_MAX) ? 0.f : __expf(ms[sp] - gm);
        sca[sp] = e;
        denom += pb[(size_t)sp * PSTRIDE + D_ + 1] * e;
    }
    float inv = 1.f / denom;   // denom > 0: l=0 always valid

    float ax = 0.f, ay = 0.f, az = 0.f, aw = 0.f;
    #pragma unroll
    for (int sp = 0; sp < NSPLIT; ++sp) {
        if (sca[sp] == 0.f) continue;
        float4 o = reinterpret_cast<const float4*>(pb + (size_t)sp * PSTRIDE)[tid];
        float s = sca[sp] * inv;
        ax += s * o.x; ay += s * o.y; az += s * o.z; aw += s * o.w;
    }
    ushort4 u;
    u.x = f2bf(ax); u.y = f2bf(ay); u.z = f2bf(az); u.w = f2bf(aw);
    reinterpret_cast<ushort4*>(ctxb)[(size_t)b * (D_ / 4) + tid] = u;
}

// ---------------------------------------------------------------------------
// fp32 -> bf16 conversion of BOTH weight matrices in one dispatch
// ---------------------------------------------------------------------------
__global__ __launch_bounds__(256) void convert2_kernel(
    const float* __restrict__ s0, const float* __restrict__ s1,
    unsigned short* __restrict__ d0, unsigned short* __restrict__ d1)
{
    const int N4 = D_ * D_ / 4;                       // 262144 float4 per matrix
    int i = blockIdx.x * 256 + threadIdx.x;           // [0, 2*N4)
    const float* s = (i < N4) ? s0 : s1;
    unsigned short* d = (i < N4) ? d0 : d1;
    int k = (i < N4) ? i : i - N4;
    float4 v = reinterpret_cast<const float4*>(s)[k];
    ushort4 u;
    u.x = f2bf(v.x); u.y = f2bf(v.y); u.z = f2bf(v.z); u.w = f2bf(v.w);
    reinterpret_cast<ushort4*>(d)[k] = u;
}

// ---------------------------------------------------------------------------
// out[m][n] = qin[m][n] + bias[n] + sum_k ctx[m][k] * W[n][k]   (bf16 MFMA)
// grid: 256 blocks = one 16x16 C tile each; 4 waves split K (256 each) + LDS reduce.
// ---------------------------------------------------------------------------
__global__ __launch_bounds__(256) void proj_kernel(
    const unsigned short* __restrict__ Abf,   // ctx bf16 [64][1024]
    const unsigned short* __restrict__ Wbf,   // W  bf16 [1024][1024]
    const float* __restrict__ qin,            // [64][1024]
    const float* __restrict__ bias,           // [1024]
    float* __restrict__ out)                  // [64][1024]
{
    const int tid  = threadIdx.x;
    const int wave = tid >> 6;
    const int lane = tid & 63;
    const int m0   = (blockIdx.x & 3) * 16;
    const int n0   = (blockIdx.x >> 2) * 16;
    const int r    = lane & 15;
    const int g    = lane >> 4;

    const bf16x8* aptr = reinterpret_cast<const bf16x8*>(
        Abf + (size_t)(m0 + r) * D_ + g * 8 + wave * 256);
    const bf16x8* bptr = reinterpret_cast<const bf16x8*>(
        Wbf + (size_t)(n0 + r) * D_ + g * 8 + wave * 256);

    f32x4 acc = {0.f, 0.f, 0.f, 0.f};
    #pragma unroll
    for (int kk = 0; kk < 8; ++kk) {          // 8 steps of K=32 -> 256 per wave
        bf16x8 a  = aptr[kk * 4];
        bf16x8 bb = bptr[kk * 4];
        acc = __builtin_amdgcn_mfma_f32_16x16x32_bf16(a, bb, acc, 0, 0, 0);
    }

    __shared__ float red[1024];
    #pragma unroll
    for (int i = 0; i < 4; ++i) red[wave * 256 + lane * 4 + i] = acc[i];
    __syncthreads();

    int ol = tid >> 2, oi = tid & 3;          // ol = original lane, oi = reg idx
    float v = red[ol * 4 + oi] + red[256 + ol * 4 + oi]
            + red[512 + ol * 4 + oi] + red[768 + ol * 4 + oi];
    int row = m0 + ((ol >> 4) * 4 + oi);      // C/D: row=(lane>>4)*4+reg
    int col = n0 + (ol & 15);                 //      col=lane&15
    out[(size_t)row * D_ + col] = qin[(size_t)row * D_ + col] + bias[col] + v;
}

// ---------------------------------------------------------------------------
extern "C" void kernel_launch(void* const* d_in, const int* in_sizes, int n_in,
                              void* d_out, int out_size, void* d_ws, size_t ws_size,
                              hipStream_t stream) {
    const float* img_q    = (const float*)d_in[0];
    const float* txt_q    = (const float*)d_in[1];
    const float* K_img    = (const float*)d_in[2];
    const float* V_img    = (const float*)d_in[3];
    const int*   img_mask = (const int*)  d_in[4];
    const float* K_txt    = (const float*)d_in[5];
    const float* V_txt    = (const float*)d_in[6];
    const int*   txt_mask = (const int*)  d_in[7];
    const float* W_img    = (const float*)d_in[8];
    const float* b_img    = (const float*)d_in[9];
    const float* W_txt    = (const float*)d_in[10];
    const float* b_txt    = (const float*)d_in[11];

    float* out_img = (float*)d_out;             // [64][1024]
    float* out_txt = (float*)d_out + B_ * D_;   // [64][1024]

    char* ws = (char*)d_ws;
    float* part = (float*)ws;                                   // 64*8*1028 f32
    size_t part_bytes = (size_t)B_ * NSPLIT * PSTRIDE * sizeof(float);
    unsigned short* Wimg_bf = (unsigned short*)(ws + part_bytes);
    unsigned short* Wtxt_bf = Wimg_bf + (size_t)D_ * D_;
    unsigned short* ctx_bf  = Wtxt_bf + (size_t)D_ * D_;

    // weight conversion (independent of attention; one dispatch)
    convert2_kernel<<<2048, 256, 0, stream>>>(W_img, W_txt, Wimg_bf, Wtxt_bf);

    // stage 1: ctx_img = attn(txt_q, K_img, V_img, img_mask); img_out = img_q + ctx@W^T + b
    attn_partial_kernel<<<B_ * NSPLIT, 512, 0, stream>>>(txt_q, K_img, V_img, img_mask, part);
    combine_kernel<<<B_, 256, 0, stream>>>(part, ctx_bf);
    proj_kernel<<<256, 256, 0, stream>>>(ctx_bf, Wimg_bf, img_q, b_img, out_img);

    // stage 2: ctx_txt = attn(img_out, K_txt, V_txt, txt_mask); txt_out = txt_q + ctx@W^T + b
    attn_partial_kernel<<<B_ * NSPLIT, 512, 0, stream>>>(out_img, K_txt, V_txt, txt_mask, part);
    combine_kernel<<<B_, 256, 0, stream>>>(part, ctx_bf);
    proj_kernel<<<256, 256, 0, stream>>>(ctx_bf, Wtxt_bf, txt_q, b_txt, out_txt);
}